// Round 9
// baseline (91.528 us; speedup 1.0000x reference)
//
#include <hip/hip_runtime.h>

#define N_Q  100000
#define N_M  5000
#define G    64
#define NC   (G * G)                          // 4096 cells
#define CS_OFF_B   64
#define SORT_OFF_B (CS_OFF_B + 16400)         // 16464, 16-aligned
#define WS_NEED    (SORT_OFF_B + N_M * 16)    // 96464 B

// ============================================================================
// build_grid: bbox -> 64x64 histogram -> scan -> scatter {x,y,ts,idx}.
// One 256-thread block, shuffle-based reductions (few syncthreads).
// Box = actual min/max, inflated cell width -> every point's raw cell index
// lands in [0,G) -> each point provably inside its cell rect (bound proof).
// Scatter order nondeterministic; queries use order-free (d2,idx) lex-min
// -> deterministic output.
// ============================================================================
__global__ __launch_bounds__(256) void build_grid(
    const float* __restrict__ maze, const float* __restrict__ ts,
    float* __restrict__ ws)
{
    __shared__ int   cnt[NC];                 // 16 KB
    __shared__ int   part[256];
    __shared__ float wred[4][4];
    const int t = threadIdx.x, lane = t & 63, wv = t >> 6;

    float mnx = 1e30f, mxx = -1e30f, mny = 1e30f, mxy = -1e30f;
    for (int i = t; i < N_M; i += 256) {
        const float x = maze[2 * i], y = maze[2 * i + 1];
        mnx = fminf(mnx, x); mxx = fmaxf(mxx, x);
        mny = fminf(mny, y); mxy = fmaxf(mxy, y);
    }
    #pragma unroll
    for (int s = 1; s < 64; s <<= 1) {
        mnx = fminf(mnx, __shfl_xor(mnx, s));
        mxx = fmaxf(mxx, __shfl_xor(mxx, s));
        mny = fminf(mny, __shfl_xor(mny, s));
        mxy = fmaxf(mxy, __shfl_xor(mxy, s));
    }
    if (lane == 0) { wred[wv][0] = mnx; wred[wv][1] = mxx; wred[wv][2] = mny; wred[wv][3] = mxy; }
    for (int i = t; i < NC; i += 256) cnt[i] = 0;
    __syncthreads();
    mnx = fminf(fminf(wred[0][0], wred[1][0]), fminf(wred[2][0], wred[3][0]));
    mxx = fmaxf(fmaxf(wred[0][1], wred[1][1]), fmaxf(wred[2][1], wred[3][1]));
    mny = fminf(fminf(wred[0][2], wred[1][2]), fminf(wred[2][2], wred[3][2]));
    mxy = fmaxf(fmaxf(wred[0][3], wred[1][3]), fmaxf(wred[2][3], wred[3][3]));

    float cwx = (mxx - mnx) * (1.0f / G) * (1.0f + 1e-5f);
    float cwy = (mxy - mny) * (1.0f / G) * (1.0f + 1e-5f);
    if (!(cwx > 0.0f)) cwx = 1.0f;            // degenerate box
    if (!(cwy > 0.0f)) cwy = 1.0f;
    const float ivx = 1.0f / cwx, ivy = 1.0f / cwy;
    if (t == 0) { ws[0] = mnx; ws[1] = mny; ws[2] = cwx; ws[3] = cwy; ws[4] = ivx; ws[5] = ivy; }

    for (int i = t; i < N_M; i += 256) {
        const float x = maze[2 * i], y = maze[2 * i + 1];
        const int cx = min(G - 1, max(0, (int)((x - mnx) * ivx)));
        const int cy = min(G - 1, max(0, (int)((y - mny) * ivy)));
        atomicAdd(&cnt[cy * G + cx], 1);
    }
    __syncthreads();

    // exclusive scan: 16 cells/thread + Hillis-Steele over 256 partials
    int* cs = (int*)((char*)ws + CS_OFF_B);
    const int base = t * 16;
    int loc[16], sum = 0;
    #pragma unroll
    for (int j = 0; j < 16; ++j) { loc[j] = sum; sum += cnt[base + j]; }
    part[t] = sum; __syncthreads();
    for (int s = 1; s < 256; s <<= 1) {
        const int v = (t >= s) ? part[t - s] : 0;
        __syncthreads();
        part[t] += v;
        __syncthreads();
    }
    const int excl = part[t] - sum;
    #pragma unroll
    for (int j = 0; j < 16; ++j) cs[base + j] = excl + loc[j];
    if (t == 0) cs[NC] = N_M;
    __syncthreads();
    #pragma unroll
    for (int j = 0; j < 16; ++j) cnt[base + j] = excl + loc[j];   // cursors
    __syncthreads();

    float4* sorted = (float4*)((char*)ws + SORT_OFF_B);
    for (int i = t; i < N_M; i += 256) {
        const float x = maze[2 * i], y = maze[2 * i + 1];
        const int cx = min(G - 1, max(0, (int)((x - mnx) * ivx)));
        const int cy = min(G - 1, max(0, (int)((y - mny) * ivy)));
        const int pos = atomicAdd(&cnt[cy * G + cx], 1);
        float4 e; e.x = x; e.y = y; e.z = ts[i]; e.w = __int_as_float(i);
        sorted[pos] = e;
    }
}

// ============================================================================
// grid_query (1 wave / block): fused 3x3 box (chunk-4 loads) -> bound ->
// ring r=2 (chunk-4) -> bound -> ballot-fused wave-cooperative brute force.
// Exact numpy IEEE sequence everywhere; (d2, orig_idx) lex-min is visit-
// order-free and duplicate-tolerant -> deterministic, bit-exact.
// NO early return: all 64 lanes stay active for ballot/cooperative brute
// (tail lanes clamp qi and skip only the final write).
// ============================================================================
__global__ __launch_bounds__(64) void grid_query(
    const float* __restrict__ q, const float* __restrict__ maze,
    const float* __restrict__ ts, const float* __restrict__ ws,
    float* __restrict__ out)
{
    const int lane = threadIdx.x;
    const int qi = blockIdx.x * 64 + lane;
    const int qc = qi < N_Q ? qi : N_Q - 1;

    const float mnx = ws[0], mny = ws[1], cwx = ws[2];
    const float cwy = ws[3], ivx = ws[4], ivy = ws[5];
    const int*    cs     = (const int*)((const char*)ws + CS_OFF_B);
    const float4* sorted = (const float4*)((const char*)ws + SORT_OFF_B);

    const float2 Q = ((const float2*)q)[qc];
    const float qx = Q.x, qy = Q.y;
    const int cx = min(G - 1, max(0, (int)((qx - mnx) * ivx)));
    const int cy = min(G - 1, max(0, (int)((qy - mny) * ivy)));

    float bd2 = 3.4e38f;
    int bidx = 0x7fffffff;

    auto cand = [&](const float4 c) {
        const float dx = __fsub_rn(qx, c.x);       // numpy-exact, no FMA
        const float dy = __fsub_rn(qy, c.y);
        const float d2 = __fadd_rn(__fmul_rn(dx, dx), __fmul_rn(dy, dy));
        const int idx = __float_as_int(c.w);
        if (d2 < bd2 || (d2 == bd2 && idx < bidx)) { bd2 = d2; bidx = idx; }
    };
    // chunk-4: 4 independent loads per waitcnt; tail duplicates are
    // idempotent under lex-min.
    auto scan4 = [&](int s, int e) {
        for (int p = s; p < e; p += 4) {
            const float4 c0 = sorted[p];
            const float4 c1 = sorted[p + 1 < e ? p + 1 : p];
            const float4 c2 = sorted[p + 2 < e ? p + 2 : p];
            const float4 c3 = sorted[p + 3 < e ? p + 3 : p];
            cand(c0); cand(c1); cand(c2); cand(c3);
        }
    };
    // all unscanned points lie outside the world-rect of cells [cx±r]x[cy±r];
    // conservative slack (>1 ulp) on the fp edge computation.
    auto bound_ok = [&](int r) -> bool {
        const float Xlo = mnx + (float)(cx - r) * cwx;
        const float Xhi = mnx + (float)(cx + r + 1) * cwx;
        const float Ylo = mny + (float)(cy - r) * cwy;
        const float Yhi = mny + (float)(cy + r + 1) * cwy;
        float lb = fminf(fminf(qx - Xlo, Xhi - qx), fminf(qy - Ylo, Yhi - qy));
        lb = lb * 0.9999f - 1e-6f;
        return (lb > 0.0f) && (lb * lb > bd2);
    };

    // ---- stage 1: 3x3 box; rows are contiguous spans; clipped rows may
    // duplicate (idempotent). 6 cs loads issued up front.
    {
        const int x0 = max(0, cx - 1), x1 = min(G - 1, cx + 1);
        const int rA = max(0, cy - 1) * G, rB = cy * G, rC = min(G - 1, cy + 1) * G;
        const int sA = cs[rA + x0], eA = cs[rA + x1 + 1];
        const int sB = cs[rB + x0], eB = cs[rB + x1 + 1];
        const int sC = cs[rC + x0], eC = cs[rC + x1 + 1];
        scan4(sA, eA); scan4(sB, eB); scan4(sC, eC);
    }
    bool resolved = bound_ok(1);

    // ---- stage 2: ring r=2 (2 row-spans + 6 single cells), only if needed
    if (__any(!resolved)) {
        if (!resolved) {
            const int X0 = max(0, cx - 2), X1 = min(G - 1, cx + 2);
            if (cy - 2 >= 0)     { const int rb = (cy - 2) * G; scan4(cs[rb + X0], cs[rb + X1 + 1]); }
            if (cy + 2 <= G - 1) { const int rb = (cy + 2) * G; scan4(cs[rb + X0], cs[rb + X1 + 1]); }
            const int Y0 = max(0, cy - 1), Y1 = min(G - 1, cy + 1);
            if (cx - 2 >= 0)     for (int y = Y0; y <= Y1; ++y) { const int c0 = y * G + cx - 2; scan4(cs[c0], cs[c0 + 1]); }
            if (cx + 2 <= G - 1) for (int y = Y0; y <= Y1; ++y) { const int c0 = y * G + cx + 2; scan4(cs[c0], cs[c0 + 1]); }
            resolved = bound_ok(2);
        }
    }

    // ---- stage 3: wave-cooperative exact brute force for unresolved lanes
    unsigned long long mask = __ballot(!resolved);
    while (mask) {
        const int l = __ffsll((unsigned long long)mask) - 1;
        mask &= mask - 1;
        const float bx = __shfl(qx, l), by = __shfl(qy, l);
        float vb = 3.4e38f; int vi = 0x7fffffff;
        #pragma unroll 4
        for (int p = lane; p < N_M; p += 64) {
            const float2 c = ((const float2*)maze)[p];
            const float dx = __fsub_rn(bx, c.x);
            const float dy = __fsub_rn(by, c.y);
            const float d2 = __fadd_rn(__fmul_rn(dx, dx), __fmul_rn(dy, dy));
            if (d2 < vb || (d2 == vb && p < vi)) { vb = d2; vi = p; }
        }
        #pragma unroll
        for (int s = 1; s < 64; s <<= 1) {
            const float ob = __shfl_xor(vb, s);
            const int   oi = __shfl_xor(vi, s);
            if (ob < vb || (ob == vb && oi < vi)) { vb = ob; vi = oi; }
        }
        if (lane == l) { bd2 = vb; bidx = (vi < N_M ? vi : N_M - 1); }
    }

    if (qi < N_Q) {
        out[2 * qi]       = maze[2 * bidx];
        out[2 * qi + 1]   = maze[2 * bidx + 1];
        out[2 * N_Q + qi] = ts[bidx];
    }
}

// ============================================================================
// Fallback: proven R5 SMEM-stream scan (66 us) if ws is too small.
// ============================================================================
#define CW   4
#define CHK  1264
#define NPAD (CW * CHK)

typedef float v2f __attribute__((ext_vector_type(2)));
typedef float v8f __attribute__((ext_vector_type(8)));

__global__ void setup_soa(const float* __restrict__ maze, float* __restrict__ ws) {
    const int i = blockIdx.x * 256 + threadIdx.x;
    if (i >= NPAD) return;
    const int c = i / CHK, k = i - c * CHK;
    float x = 1e30f, y = 1e30f;
    const int g = c * 1250 + k;
    if (k < 1250) { x = -maze[2 * g]; y = -maze[2 * g + 1]; }
    ws[i] = x;
    ws[NPAD + i] = y;
}

#define LDX0(D) asm volatile("s_load_dwordx8 %0, %1, 0x0"    : "=s"(D) : "s"(xb))
#define LDX1(D) asm volatile("s_load_dwordx8 %0, %1, 0x20"   : "=s"(D) : "s"(xb))
#define LDY0(D) asm volatile("s_load_dwordx8 %0, %1, 0x4f00" : "=s"(D) : "s"(xb))
#define LDY1(D) asm volatile("s_load_dwordx8 %0, %1, 0x4f20" : "=s"(D) : "s"(xb))
#define WAIT4(a,b,c,d) asm volatile("s_waitcnt lgkmcnt(0)" : "+s"(a), "+s"(b), "+s"(c), "+s"(d))

#define PSTEP(X8, Y8, J) do {                                                 \
    v2f px_ = __builtin_shufflevector(X8, X8, 2*(J), 2*(J)+1);                \
    v2f py_ = __builtin_shufflevector(Y8, Y8, 2*(J), 2*(J)+1);                \
    v2f dx_, dy_;                                                             \
    asm("v_pk_add_f32 %0, %1, %2" : "=v"(dx_) : "s"(px_), "v"(qxx));          \
    asm("v_pk_add_f32 %0, %1, %2" : "=v"(dy_) : "s"(py_), "v"(qyy));          \
    asm("v_pk_mul_f32 %0, %0, %0" : "+v"(dx_));                               \
    asm("v_pk_mul_f32 %0, %0, %0" : "+v"(dy_));                               \
    asm("v_pk_add_f32 %0, %0, %1" : "+v"(dx_) : "v"(dy_));                    \
    float a_ = dx_.x, b_ = dx_.y;                                             \
    asm("v_min3_f32 %0, %1, %2, %0" : "+v"(bm) : "v"(a_), "v"(b_));           \
} while (0)

#define COMP(X0, X1, Y0, Y1, B) do {                                          \
    PSTEP(X0, Y0, 0); PSTEP(X0, Y0, 1); PSTEP(X0, Y0, 2); PSTEP(X0, Y0, 3);   \
    PSTEP(X1, Y1, 0); PSTEP(X1, Y1, 1); PSTEP(X1, Y1, 2); PSTEP(X1, Y1, 3);   \
    bb = (bm < prev) ? (B) : bb; prev = bm;                                   \
} while (0)

__global__ __launch_bounds__(256) void nn_scan(
    const float* __restrict__ q, const float* __restrict__ maze,
    const float* __restrict__ ts, const float* __restrict__ ws,
    float* __restrict__ out)
{
    __shared__ float sval[CW][64];
    __shared__ int   sidx[CW][64];
    const int lane = threadIdx.x & 63;
    const int wv   = __builtin_amdgcn_readfirstlane((int)(threadIdx.x >> 6));
    const int qi   = blockIdx.x * 64 + lane;
    const int qc   = qi < N_Q ? qi : N_Q - 1;
    const float2 Q = ((const float2*)q)[qc];
    const v2f qxx = { Q.x, Q.x };
    const v2f qyy = { Q.y, Q.y };
    unsigned long long xb = (unsigned long long)(const void*)(ws + (size_t)wv * CHK);
    v8f ax0, ax1, ay0, ay1, bx0, bx1, by0, by1;
    LDX0(ax0); LDX1(ax1); LDY0(ay0); LDY1(ay1); xb += 64;
    float bm = 3.4e38f, prev = 3.4e38f;
    int bb = 0;
    #pragma unroll 1
    for (int k = 0; k < 39; ++k) {
        WAIT4(ax0, ax1, ay0, ay1);
        LDX0(bx0); LDX1(bx1); LDY0(by0); LDY1(by1); xb += 64;
        COMP(ax0, ax1, ay0, ay1, 2 * k);
        WAIT4(bx0, bx1, by0, by1);
        LDX0(ax0); LDX1(ax1); LDY0(ay0); LDY1(ay1); xb += 64;
        COMP(bx0, bx1, by0, by1, 2 * k + 1);
    }
    WAIT4(ax0, ax1, ay0, ay1);
    COMP(ax0, ax1, ay0, ay1, 78);
    int fk = 0x7fffffff;
    {
        const float* xs = ws + (size_t)wv * CHK + (size_t)bb * 16;
        #pragma unroll
        for (int j = 0; j < 16; ++j) {
            const float dx = __fadd_rn(Q.x, xs[j]);
            const float dy = __fadd_rn(Q.y, xs[j + NPAD]);
            const float d2 = __fadd_rn(__fmul_rn(dx, dx), __fmul_rn(dy, dy));
            if (d2 == bm) fk = min(fk, bb * 16 + j);
        }
    }
    const int kloc = fk < 1250 ? fk : 1249;
    sval[wv][lane] = bm;
    sidx[wv][lane] = wv * 1250 + kloc;
    __syncthreads();
    if (wv == 0 && qi < N_Q) {
        float bv = sval[0][lane];
        int   bg = sidx[0][lane];
        #pragma unroll
        for (int c = 1; c < CW; ++c) {
            const float v = sval[c][lane];
            const int   g = sidx[c][lane];
            if (v < bv || (v == bv && g < bg)) { bv = v; bg = g; }
        }
        const float2 bp = ((const float2*)maze)[bg];
        out[2 * qi]       = bp.x;
        out[2 * qi + 1]   = bp.y;
        out[2 * N_Q + qi] = ts[bg];
    }
}

extern "C" void kernel_launch(void* const* d_in, const int* in_sizes, int n_in,
                              void* d_out, int out_size, void* d_ws, size_t ws_size,
                              hipStream_t stream) {
    const float* q    = (const float*)d_in[0];  // euclidean_data [N,2]
    const float* maze = (const float*)d_in[1];  // maze_points   [M,2]
    const float* ts   = (const float*)d_in[2];  // ts_proj       [M]
    float* out = (float*)d_out;                 // [N*2] proj_pos ++ [N] linear_pos

    if (ws_size >= (size_t)WS_NEED) {
        build_grid<<<1, 256, 0, stream>>>(maze, ts, (float*)d_ws);
        grid_query<<<(N_Q + 63) / 64, 64, 0, stream>>>(q, maze, ts,
                                                       (const float*)d_ws, out);
    } else {
        setup_soa<<<(NPAD + 255) / 256, 256, 0, stream>>>(maze, (float*)d_ws);
        nn_scan<<<(N_Q + 63) / 64, 256, 0, stream>>>(q, maze, ts,
                                                     (const float*)d_ws, out);
    }
}

// Round 10
// 73.646 us; speedup vs baseline: 1.2428x; 1.2428x over previous
//
#include <hip/hip_runtime.h>

#define N_Q  100000
#define N_M  5000
#define G    64
#define NC   (G * G)                 // 4096 cells
#define RMAX 4                       // ring cap; unresolved -> brute overflow
#define CS_OFF_B   64
#define SORT_OFF_B (CS_OFF_B + 16400)         // 16464 (cs: 4097*4, padded)
#define OVF_OFF_B  (SORT_OFF_B + N_M * 16)    // 96464
#define WS_NEED    (OVF_OFF_B + N_Q * 4)      // 496464 B (R7 proved ws >= this)

// ============================================================================
// build_grid (R7, proven): bbox -> histogram -> scan -> scatter {x,y,ts,idx}.
// Box = actual min/max, inflated cell width -> every point provably inside its
// cell rect (ring bound proof). Scatter order nondeterministic; queries use
// order-free (d2,idx) lex-min -> deterministic output.
// ============================================================================
__global__ __launch_bounds__(1024) void build_grid(
    const float* __restrict__ maze, const float* __restrict__ ts,
    float* __restrict__ ws)
{
    __shared__ float red[1024];
    __shared__ int   part[1024];
    __shared__ int   cnt[NC];        // 16 KB
    const int t = threadIdx.x;
    if (t == 0) ((int*)ws)[8] = 0;   // reset overflow counter (every call)

    float mnx = 1e30f, mxx = -1e30f, mny = 1e30f, mxy = -1e30f;
    for (int i = t; i < N_M; i += 1024) {
        const float x = maze[2 * i], y = maze[2 * i + 1];
        mnx = fminf(mnx, x); mxx = fmaxf(mxx, x);
        mny = fminf(mny, y); mxy = fmaxf(mxy, y);
    }
    auto reduce = [&](float v, bool domin) -> float {
        red[t] = v; __syncthreads();
        for (int s = 512; s > 0; s >>= 1) {
            if (t < s) {
                const float o = red[t + s];
                red[t] = domin ? fminf(red[t], o) : fmaxf(red[t], o);
            }
            __syncthreads();
        }
        const float r = red[0]; __syncthreads(); return r;
    };
    mnx = reduce(mnx, true);  mxx = reduce(mxx, false);
    mny = reduce(mny, true);  mxy = reduce(mxy, false);

    float cwx = (mxx - mnx) * (1.0f / G) * (1.0f + 1e-5f);
    float cwy = (mxy - mny) * (1.0f / G) * (1.0f + 1e-5f);
    if (!(cwx > 0.0f)) cwx = 1.0f;   // degenerate box
    if (!(cwy > 0.0f)) cwy = 1.0f;
    const float ivx = 1.0f / cwx, ivy = 1.0f / cwy;
    if (t == 0) {
        ws[0] = mnx; ws[1] = mny; ws[2] = cwx;
        ws[3] = cwy; ws[4] = ivx; ws[5] = ivy;
    }

    for (int i = t; i < NC; i += 1024) cnt[i] = 0;
    __syncthreads();
    for (int i = t; i < N_M; i += 1024) {
        const float x = maze[2 * i], y = maze[2 * i + 1];
        const int cx = min(G - 1, max(0, (int)((x - mnx) * ivx)));
        const int cy = min(G - 1, max(0, (int)((y - mny) * ivy)));
        atomicAdd(&cnt[cy * G + cx], 1);
    }
    __syncthreads();

    int* cs = (int*)((char*)ws + CS_OFF_B);
    const int base = t * 4;
    int loc[4], sum = 0;
    #pragma unroll
    for (int j = 0; j < 4; ++j) { loc[j] = sum; sum += cnt[base + j]; }
    part[t] = sum; __syncthreads();
    for (int s = 1; s < 1024; s <<= 1) {
        const int v = (t >= s) ? part[t - s] : 0;
        __syncthreads();
        part[t] += v;
        __syncthreads();
    }
    const int excl = part[t] - sum;
    #pragma unroll
    for (int j = 0; j < 4; ++j) cs[base + j] = excl + loc[j];
    if (t == 0) cs[NC] = N_M;
    __syncthreads();
    #pragma unroll
    for (int j = 0; j < 4; ++j) cnt[base + j] = excl + loc[j];  // cursors
    __syncthreads();

    float4* sorted = (float4*)((char*)ws + SORT_OFF_B);
    for (int i = t; i < N_M; i += 1024) {
        const float x = maze[2 * i], y = maze[2 * i + 1];
        const int cx = min(G - 1, max(0, (int)((x - mnx) * ivx)));
        const int cy = min(G - 1, max(0, (int)((y - mny) * ivy)));
        const int pos = atomicAdd(&cnt[cy * G + cx], 1);
        float4 e; e.x = x; e.y = y; e.z = ts[i]; e.w = __int_as_float(i);
        sorted[pos] = e;
    }
}

// ============================================================================
// grid_query: rings to RMAX with CHUNK-8 loads (8 independent dwordx4 per
// waitcnt; tail duplicates idempotent under lex-min). Rows of cells are
// contiguous in `sorted` -> one span per row. Exact numpy IEEE sequence;
// (d2, orig_idx) lex-min is visit-order-free -> deterministic, bit-exact.
// Unresolved after RMAX -> push to overflow list (separate brute kernel).
// ============================================================================
__global__ __launch_bounds__(256) void grid_query(
    const float* __restrict__ q, const float* __restrict__ maze,
    const float* __restrict__ ts, float* __restrict__ ws,
    float* __restrict__ out)
{
    const int qi = blockIdx.x * 256 + threadIdx.x;
    if (qi >= N_Q) return;

    const float mnx = ws[0], mny = ws[1], cwx = ws[2];
    const float cwy = ws[3], ivx = ws[4], ivy = ws[5];
    const int*    cs     = (const int*)((const char*)ws + CS_OFF_B);
    const float4* sorted = (const float4*)((const char*)ws + SORT_OFF_B);

    const float2 Q = ((const float2*)q)[qi];
    const float qx = Q.x, qy = Q.y;
    const int cx = min(G - 1, max(0, (int)((qx - mnx) * ivx)));
    const int cy = min(G - 1, max(0, (int)((qy - mny) * ivy)));

    float bd2 = 3.4e38f;
    int bidx = 0x7fffffff;

    auto cand = [&](const float4 c) {
        const float dx = __fsub_rn(qx, c.x);       // numpy-exact, no FMA
        const float dy = __fsub_rn(qy, c.y);
        const float d2 = __fadd_rn(__fmul_rn(dx, dx), __fmul_rn(dy, dy));
        const int idx = __float_as_int(c.w);
        if (d2 < bd2 || (d2 == bd2 && idx < bidx)) { bd2 = d2; bidx = idx; }
    };
    auto scan8 = [&](int s, int e) {              // 8 loads in flight / waitcnt
        for (int p = s; p < e; p += 8) {
            const float4 c0 = sorted[p];
            const float4 c1 = sorted[p + 1 < e ? p + 1 : p];
            const float4 c2 = sorted[p + 2 < e ? p + 2 : p];
            const float4 c3 = sorted[p + 3 < e ? p + 3 : p];
            const float4 c4 = sorted[p + 4 < e ? p + 4 : p];
            const float4 c5 = sorted[p + 5 < e ? p + 5 : p];
            const float4 c6 = sorted[p + 6 < e ? p + 6 : p];
            const float4 c7 = sorted[p + 7 < e ? p + 7 : p];
            cand(c0); cand(c1); cand(c2); cand(c3);
            cand(c4); cand(c5); cand(c6); cand(c7);
        }
    };
    auto scan4 = [&](int s, int e) {              // for tiny single cells
        for (int p = s; p < e; p += 4) {
            const float4 c0 = sorted[p];
            const float4 c1 = sorted[p + 1 < e ? p + 1 : p];
            const float4 c2 = sorted[p + 2 < e ? p + 2 : p];
            const float4 c3 = sorted[p + 3 < e ? p + 3 : p];
            cand(c0); cand(c1); cand(c2); cand(c3);
        }
    };
    // all unscanned points lie outside the world-rect of cells [cx±r]x[cy±r];
    // conservative slack (>1 ulp) on the fp edge computation.
    auto bound_ok = [&](int r) -> bool {
        const float Xlo = mnx + (float)(cx - r) * cwx;
        const float Xhi = mnx + (float)(cx + r + 1) * cwx;
        const float Ylo = mny + (float)(cy - r) * cwy;
        const float Yhi = mny + (float)(cy + r + 1) * cwy;
        float lb = fminf(fminf(qx - Xlo, Xhi - qx), fminf(qy - Ylo, Yhi - qy));
        lb = lb * 0.9999f - 1e-6f;
        return (lb > 0.0f) && (lb * lb > bd2);
    };

    // ---- stage 1: 3x3 box, one contiguous span per row (clipped rows may
    // duplicate cells across rows at the border -> idempotent).
    {
        const int x0 = max(0, cx - 1), x1 = min(G - 1, cx + 1);
        const int rA = max(0, cy - 1) * G, rB = cy * G, rC = min(G - 1, cy + 1) * G;
        const int sA = cs[rA + x0], eA = cs[rA + x1 + 1];
        const int sB = cs[rB + x0], eB = cs[rB + x1 + 1];
        const int sC = cs[rC + x0], eC = cs[rC + x1 + 1];
        scan8(sA, eA); scan8(sB, eB); scan8(sC, eC);
    }
    bool resolved = bound_ok(1);

    // ---- rings r=2..RMAX (top/bottom = one span each; sides = single cells)
    for (int r = 2; r <= RMAX && __any(!resolved); ++r) {
        if (!resolved) {
            const int X0 = max(0, cx - r), X1 = min(G - 1, cx + r);
            if (cy - r >= 0)     { const int rb = (cy - r) * G; scan8(cs[rb + X0], cs[rb + X1 + 1]); }
            if (cy + r <= G - 1) { const int rb = (cy + r) * G; scan8(cs[rb + X0], cs[rb + X1 + 1]); }
            const int Y0 = max(0, cy - r + 1), Y1 = min(G - 1, cy + r - 1);
            if (cx - r >= 0)     for (int y = Y0; y <= Y1; ++y) { const int c0 = y * G + cx - r; scan4(cs[c0], cs[c0 + 1]); }
            if (cx + r <= G - 1) for (int y = Y0; y <= Y1; ++y) { const int c0 = y * G + cx + r; scan4(cs[c0], cs[c0 + 1]); }
            resolved = bound_ok(r);
        }
    }

    if (resolved) {
        out[2 * qi]       = maze[2 * bidx];
        out[2 * qi + 1]   = maze[2 * bidx + 1];
        out[2 * N_Q + qi] = ts[bidx];
    } else {
        int* ovfc = (int*)ws + 8;
        const int pos = atomicAdd(ovfc, 1);
        ((int*)((char*)ws + OVF_OFF_B))[pos] = qi;  // brute kernel finishes it
    }
}

// ============================================================================
// brute_overflow (R7, proven): one wave per unresolved query (grid-stride).
// Identical IEEE sequence, lex shuffle-reduce. List order nondeterministic but
// each query writes only its own slot -> deterministic.
// ============================================================================
__global__ __launch_bounds__(256) void brute_overflow(
    const float* __restrict__ q, const float* __restrict__ maze,
    const float* __restrict__ ts, const float* __restrict__ ws,
    float* __restrict__ out)
{
    const int cnt = ((const int*)ws)[8];
    const int* ovl = (const int*)((const char*)ws + OVF_OFF_B);
    const int wave  = (blockIdx.x * 256 + threadIdx.x) >> 6;
    const int lane  = threadIdx.x & 63;
    const int nwave = gridDim.x * 4;

    for (int w = wave; w < cnt; w += nwave) {
        const int qi = ovl[w];
        const float qx = q[2 * qi], qy = q[2 * qi + 1];
        float bd2 = 3.4e38f; int bidx = 0x7fffffff;
        for (int p = lane; p < N_M; p += 64) {
            const float2 c = ((const float2*)maze)[p];
            const float dx = __fsub_rn(qx, c.x);
            const float dy = __fsub_rn(qy, c.y);
            const float d2 = __fadd_rn(__fmul_rn(dx, dx), __fmul_rn(dy, dy));
            if (d2 < bd2 || (d2 == bd2 && p < bidx)) { bd2 = d2; bidx = p; }
        }
        #pragma unroll
        for (int s = 1; s < 64; s <<= 1) {
            const float ob = __shfl_xor(bd2, s);
            const int   oi = __shfl_xor(bidx, s);
            if (ob < bd2 || (ob == bd2 && oi < bidx)) { bd2 = ob; bidx = oi; }
        }
        if (lane == 0) {
            out[2 * qi]       = maze[2 * bidx];
            out[2 * qi + 1]   = maze[2 * bidx + 1];
            out[2 * N_Q + qi] = ts[bidx];
        }
    }
}

// ============================================================================
// Fallback: proven R5 SMEM-stream scan (66 us) if ws is too small.
// ============================================================================
#define CW   4
#define CHK  1264
#define NPAD (CW * CHK)

typedef float v2f __attribute__((ext_vector_type(2)));
typedef float v8f __attribute__((ext_vector_type(8)));

__global__ void setup_soa(const float* __restrict__ maze, float* __restrict__ ws) {
    const int i = blockIdx.x * 256 + threadIdx.x;
    if (i >= NPAD) return;
    const int c = i / CHK, k = i - c * CHK;
    float x = 1e30f, y = 1e30f;
    const int g = c * 1250 + k;
    if (k < 1250) { x = -maze[2 * g]; y = -maze[2 * g + 1]; }
    ws[i] = x;
    ws[NPAD + i] = y;
}

#define LDX0(D) asm volatile("s_load_dwordx8 %0, %1, 0x0"    : "=s"(D) : "s"(xb))
#define LDX1(D) asm volatile("s_load_dwordx8 %0, %1, 0x20"   : "=s"(D) : "s"(xb))
#define LDY0(D) asm volatile("s_load_dwordx8 %0, %1, 0x4f00" : "=s"(D) : "s"(xb))
#define LDY1(D) asm volatile("s_load_dwordx8 %0, %1, 0x4f20" : "=s"(D) : "s"(xb))
#define WAIT4(a,b,c,d) asm volatile("s_waitcnt lgkmcnt(0)" : "+s"(a), "+s"(b), "+s"(c), "+s"(d))

#define PSTEP(X8, Y8, J) do {                                                 \
    v2f px_ = __builtin_shufflevector(X8, X8, 2*(J), 2*(J)+1);                \
    v2f py_ = __builtin_shufflevector(Y8, Y8, 2*(J), 2*(J)+1);                \
    v2f dx_, dy_;                                                             \
    asm("v_pk_add_f32 %0, %1, %2" : "=v"(dx_) : "s"(px_), "v"(qxx));          \
    asm("v_pk_add_f32 %0, %1, %2" : "=v"(dy_) : "s"(py_), "v"(qyy));          \
    asm("v_pk_mul_f32 %0, %0, %0" : "+v"(dx_));                               \
    asm("v_pk_mul_f32 %0, %0, %0" : "+v"(dy_));                               \
    asm("v_pk_add_f32 %0, %0, %1" : "+v"(dx_) : "v"(dy_));                    \
    float a_ = dx_.x, b_ = dx_.y;                                             \
    asm("v_min3_f32 %0, %1, %2, %0" : "+v"(bm) : "v"(a_), "v"(b_));           \
} while (0)

#define COMP(X0, X1, Y0, Y1, B) do {                                          \
    PSTEP(X0, Y0, 0); PSTEP(X0, Y0, 1); PSTEP(X0, Y0, 2); PSTEP(X0, Y0, 3);   \
    PSTEP(X1, Y1, 0); PSTEP(X1, Y1, 1); PSTEP(X1, Y1, 2); PSTEP(X1, Y1, 3);   \
    bb = (bm < prev) ? (B) : bb; prev = bm;                                   \
} while (0)

__global__ __launch_bounds__(256) void nn_scan(
    const float* __restrict__ q, const float* __restrict__ maze,
    const float* __restrict__ ts, const float* __restrict__ ws,
    float* __restrict__ out)
{
    __shared__ float sval[CW][64];
    __shared__ int   sidx[CW][64];
    const int lane = threadIdx.x & 63;
    const int wv   = __builtin_amdgcn_readfirstlane((int)(threadIdx.x >> 6));
    const int qi   = blockIdx.x * 64 + lane;
    const int qc   = qi < N_Q ? qi : N_Q - 1;
    const float2 Q = ((const float2*)q)[qc];
    const v2f qxx = { Q.x, Q.x };
    const v2f qyy = { Q.y, Q.y };
    unsigned long long xb = (unsigned long long)(const void*)(ws + (size_t)wv * CHK);
    v8f ax0, ax1, ay0, ay1, bx0, bx1, by0, by1;
    LDX0(ax0); LDX1(ax1); LDY0(ay0); LDY1(ay1); xb += 64;
    float bm = 3.4e38f, prev = 3.4e38f;
    int bb = 0;
    #pragma unroll 1
    for (int k = 0; k < 39; ++k) {
        WAIT4(ax0, ax1, ay0, ay1);
        LDX0(bx0); LDX1(bx1); LDY0(by0); LDY1(by1); xb += 64;
        COMP(ax0, ax1, ay0, ay1, 2 * k);
        WAIT4(bx0, bx1, by0, by1);
        LDX0(ax0); LDX1(ax1); LDY0(ay0); LDY1(ay1); xb += 64;
        COMP(bx0, bx1, by0, by1, 2 * k + 1);
    }
    WAIT4(ax0, ax1, ay0, ay1);
    COMP(ax0, ax1, ay0, ay1, 78);
    int fk = 0x7fffffff;
    {
        const float* xs = ws + (size_t)wv * CHK + (size_t)bb * 16;
        #pragma unroll
        for (int j = 0; j < 16; ++j) {
            const float dx = __fadd_rn(Q.x, xs[j]);
            const float dy = __fadd_rn(Q.y, xs[j + NPAD]);
            const float d2 = __fadd_rn(__fmul_rn(dx, dx), __fmul_rn(dy, dy));
            if (d2 == bm) fk = min(fk, bb * 16 + j);
        }
    }
    const int kloc = fk < 1250 ? fk : 1249;
    sval[wv][lane] = bm;
    sidx[wv][lane] = wv * 1250 + kloc;
    __syncthreads();
    if (wv == 0 && qi < N_Q) {
        float bv = sval[0][lane];
        int   bg = sidx[0][lane];
        #pragma unroll
        for (int c = 1; c < CW; ++c) {
            const float v = sval[c][lane];
            const int   g = sidx[c][lane];
            if (v < bv || (v == bv && g < bg)) { bv = v; bg = g; }
        }
        const float2 bp = ((const float2*)maze)[bg];
        out[2 * qi]       = bp.x;
        out[2 * qi + 1]   = bp.y;
        out[2 * N_Q + qi] = ts[bg];
    }
}

extern "C" void kernel_launch(void* const* d_in, const int* in_sizes, int n_in,
                              void* d_out, int out_size, void* d_ws, size_t ws_size,
                              hipStream_t stream) {
    const float* q    = (const float*)d_in[0];  // euclidean_data [N,2]
    const float* maze = (const float*)d_in[1];  // maze_points   [M,2]
    const float* ts   = (const float*)d_in[2];  // ts_proj       [M]
    float* out = (float*)d_out;                 // [N*2] proj_pos ++ [N] linear_pos

    if (ws_size >= (size_t)WS_NEED) {
        build_grid<<<1, 1024, 0, stream>>>(maze, ts, (float*)d_ws);
        grid_query<<<(N_Q + 255) / 256, 256, 0, stream>>>(q, maze, ts,
                                                          (float*)d_ws, out);
        brute_overflow<<<256, 256, 0, stream>>>(q, maze, ts, (const float*)d_ws, out);
    } else {
        setup_soa<<<(NPAD + 255) / 256, 256, 0, stream>>>(maze, (float*)d_ws);
        nn_scan<<<(N_Q + 63) / 64, 256, 0, stream>>>(q, maze, ts,
                                                     (const float*)d_ws, out);
    }
}